// Round 1
// baseline (977.219 us; speedup 1.0000x reference)
//
#include <hip/hip_runtime.h>

// Scatter-sum: out[node] += H[edge] for each edge with X_node[edge] == node.
// H: [NUM_EDGES=2e6, D=32] f32, X_node: [2e6] int32, out: [100000, 32] f32.
//
// R4: counting-sort + LDS accumulation. R3's counters showed WRITE_SIZE ==
// 64M * 4B exactly: device-scope f32 atomics write through L2 to the fabric
// and the kernel is atomic-OP-RATE bound (313 G/s), not BW bound. So we
// eliminate the 64M f32 atomics:
//   1) histogram edges into 64-node bins (node>>6)
//   2) exclusive scan of bin counts
//   3) scatter packed (local<<24 | edge) ids into bin-sorted order
//   4) per-bin gather: LDS acc[64][32] += H rows (ds_add_f32), then one
//      clean coalesced store per output element (no out memset needed).
// Device atomics: 64M f32 -> ~2.8M int. WRITE: 256 MB -> ~21 MB.

#define NPB   64      // nodes per bin
#define SHIFT 6       // log2(NPB)
#define MAXBINS 2048  // scan kernel capacity (100000/64 = 1563)

__global__ void hist_kernel(const int* __restrict__ X, int E,
                            int* __restrict__ counts, int nbins) {
    extern __shared__ int h[];
    for (int i = threadIdx.x; i < nbins; i += blockDim.x) h[i] = 0;
    __syncthreads();
    int stride = gridDim.x * blockDim.x;
    for (long long i = (long long)blockIdx.x * blockDim.x + threadIdx.x; i < E;
         i += stride)
        atomicAdd(&h[X[i] >> SHIFT], 1);
    __syncthreads();
    for (int i = threadIdx.x; i < nbins; i += blockDim.x) {
        int c = h[i];
        if (c) atomicAdd(&counts[i], c);
    }
}

// Single block, 1024 threads, handles nbins <= 2048 via pair-per-thread.
__global__ void scan_kernel(const int* __restrict__ counts,
                            int* __restrict__ start,
                            int* __restrict__ cursor, int nbins) {
    __shared__ int s[1024];
    int tid = threadIdx.x;
    int i0 = 2 * tid, i1 = 2 * tid + 1;
    int c0 = (i0 < nbins) ? counts[i0] : 0;
    int c1 = (i1 < nbins) ? counts[i1] : 0;
    int pair = c0 + c1;
    s[tid] = pair;
    __syncthreads();
    for (int off = 1; off < 1024; off <<= 1) {
        int add = (tid >= off) ? s[tid - off] : 0;
        __syncthreads();
        s[tid] += add;
        __syncthreads();
    }
    int excl = s[tid] - pair;   // exclusive prefix at element i0
    if (i0 < nbins) { start[i0] = excl;      cursor[i0] = excl;      }
    if (i1 < nbins) { start[i1] = excl + c0; cursor[i1] = excl + c0; }
}

__global__ void scatter_kernel(const int* __restrict__ X, int E,
                               int* __restrict__ cursor,
                               unsigned* __restrict__ sorted) {
    long long i = (long long)blockIdx.x * blockDim.x + threadIdx.x;
    if (i >= E) return;
    int node = X[(int)i];
    int bin  = node >> SHIFT;
    int pos  = atomicAdd(&cursor[bin], 1);
    sorted[pos] = (unsigned)i | ((unsigned)(node & (NPB - 1)) << 24);
}

__global__ __launch_bounds__(256) void gather_kernel(
        const float* __restrict__ H,
        const unsigned* __restrict__ sorted,
        const int* __restrict__ start,
        float* __restrict__ out,
        int E, int nbins, int nnodes) {
    __shared__ float acc[NPB * 32];
    int bin = blockIdx.x;
    int s   = start[bin];
    int end = (bin + 1 < nbins) ? start[bin + 1] : E;

    for (int i = threadIdx.x; i < NPB * 32; i += 256) acc[i] = 0.0f;
    __syncthreads();

    int col  = threadIdx.x & 31;   // lane->col: 2 lanes/bank on ds_add = free
    int slot = threadIdx.x >> 5;   // 8 edges in flight per block
    for (int i = s + slot; i < end; i += 8) {
        unsigned p = sorted[i];            // broadcast within 32-lane group
        int edge  = (int)(p & 0xFFFFFFu);
        int local = (int)(p >> 24);
        float v = H[(long long)edge * 32 + col];   // 128B contiguous per edge
        unsafeAtomicAdd(&acc[local * 32 + col], v);  // ds_add_f32
    }
    __syncthreads();

    int node_base = bin << SHIFT;
    for (int i = threadIdx.x; i < NPB * 32; i += 256) {
        int node = node_base + (i >> 5);
        if (node < nnodes) out[(long long)node * 32 + (i & 31)] = acc[i];
    }
}

// Fallback (R3): one thread per (edge,col), straight device atomics.
__global__ void AggrSum_46299747451335_kernel(const float* __restrict__ H,
                                              const int* __restrict__ X_node,
                                              float* __restrict__ out,
                                              int num_edges) {
    long long t = (long long)blockIdx.x * blockDim.x + threadIdx.x;
    long long total = (long long)num_edges * 32;
    if (t >= total) return;
    int edge = (int)(t >> 5);
    int col  = (int)(t & 31);
    int node = X_node[edge];
    float v = H[t];
    unsafeAtomicAdd(&out[(long long)node * 32 + col], v);
}

extern "C" void kernel_launch(void* const* d_in, const int* in_sizes, int n_in,
                              void* d_out, int out_size, void* d_ws, size_t ws_size,
                              hipStream_t stream) {
    const float* H      = (const float*)d_in[0];
    const int*   X_node = (const int*)d_in[1];
    float*       out    = (float*)d_out;

    const int num_edges = in_sizes[0] / 32;   // H is [num_edges, 32]
    const int num_nodes = out_size / 32;      // out is [num_nodes, 32]
    const int nbins     = (num_nodes + NPB - 1) >> SHIFT;

    size_t need = (size_t)3 * MAXBINS * sizeof(int)
                + (size_t)num_edges * sizeof(unsigned);

    if (nbins <= MAXBINS && num_edges < (1 << 24) && ws_size >= need) {
        char* ws = (char*)d_ws;
        int*      counts = (int*)(ws);
        int*      start  = (int*)(ws + (size_t)MAXBINS * sizeof(int));
        int*      cursor = (int*)(ws + (size_t)2 * MAXBINS * sizeof(int));
        unsigned* sorted = (unsigned*)(ws + (size_t)3 * MAXBINS * sizeof(int));

        hipMemsetAsync(counts, 0, (size_t)nbins * sizeof(int), stream);

        hist_kernel<<<256, 256, nbins * sizeof(int), stream>>>(
            X_node, num_edges, counts, nbins);

        scan_kernel<<<1, 1024, 0, stream>>>(counts, start, cursor, nbins);

        int sgrid = (num_edges + 255) / 256;
        scatter_kernel<<<sgrid, 256, 0, stream>>>(X_node, num_edges, cursor, sorted);

        gather_kernel<<<nbins, 256, 0, stream>>>(
            H, sorted, start, out, num_edges, nbins, num_nodes);
    } else {
        // Fallback: proven R3 path.
        hipMemsetAsync(d_out, 0, (size_t)out_size * sizeof(float), stream);
        long long total_threads = (long long)num_edges * 32;
        int block = 256;
        long long grid = (total_threads + block - 1) / block;
        AggrSum_46299747451335_kernel<<<(dim3)(unsigned)grid, block, 0, stream>>>(
            H, X_node, out, num_edges);
    }
}

// Round 2
// 667.175 us; speedup vs baseline: 1.4647x; 1.4647x over previous
//
#include <hip/hip_runtime.h>

// Scatter-sum: out[node] += H[edge] for each edge with X_node[edge] == node.
// H: [NUM_EDGES=2e6, D=32] f32, X_node: [2e6] int32, out: [100000, 32] f32.
//
// R5: deterministic counting sort (no contended global atomics) + MLP gather.
// R4 post-mortem: gather was latency-bound (1 load-chain per 32-lane group,
// 354 GB/s) and scatter's 2M returning atomics on 1563 cursor words ate
// ~570 us at the coherence point. Fixes:
//   1) hist[bin][chunk] + two tiny scans -> exact scatter offsets; scatter
//      uses only per-block LDS cursors (ds_add_rtn, ~5 ops/counter).
//   2) gather unrolled x4: 4 independent sorted loads -> 4 independent H-row
//      loads in flight per 32-lane group (32 edges/block in flight).
// Ideal traffic ~300 MB => ~50 us floor; no out memset (every elem stored).

#define NPB     64      // nodes per bin
#define SHIFT   6       // log2(NPB)
#define MAXBINS 2048    // capacity (100000/64 = 1563)
#define NB      256     // number of edge chunks (hist/scatter blocks)

// ---- 1) per-chunk histogram: hist[b*NB + blk] = #edges of bin b in chunk blk
__global__ __launch_bounds__(1024) void hist_kernel(
        const int* __restrict__ X, int E, int chunk,
        int* __restrict__ hist, int nbins) {
    __shared__ int h[MAXBINS];
    int blk = blockIdx.x;
    for (int b = threadIdx.x; b < nbins; b += 1024) h[b] = 0;
    __syncthreads();
    int beg = blk * chunk;
    int end = min(beg + chunk, E);
    for (int i = beg + threadIdx.x; i < end; i += 1024)
        atomicAdd(&h[X[i] >> SHIFT], 1);
    __syncthreads();
    for (int b = threadIdx.x; b < nbins; b += 1024)
        hist[b * NB + blk] = h[b];
}

// ---- 2a) per-bin scan over its NB=256 chunk counts (in place, exclusive);
//          binTotal[b] = bin size.
__global__ __launch_bounds__(256) void scanA_kernel(
        int* __restrict__ hist, int* __restrict__ binTotal) {
    __shared__ int s[NB];
    int b = blockIdx.x, tid = threadIdx.x;
    int v = hist[b * NB + tid];
    s[tid] = v;
    __syncthreads();
    for (int off = 1; off < NB; off <<= 1) {
        int add = (tid >= off) ? s[tid - off] : 0;
        __syncthreads();
        s[tid] += add;
        __syncthreads();
    }
    hist[b * NB + tid] = s[tid] - v;          // exclusive within bin
    if (tid == NB - 1) binTotal[b] = s[NB - 1];
}

// ---- 2b) exclusive scan of binTotal -> binStart[0..nbins], single block.
__global__ __launch_bounds__(1024) void scanB_kernel(
        const int* __restrict__ binTotal, int* __restrict__ binStart,
        int nbins) {
    __shared__ int s[1024];
    int tid = threadIdx.x;
    int i0 = 2 * tid, i1 = 2 * tid + 1;
    int c0 = (i0 < nbins) ? binTotal[i0] : 0;
    int c1 = (i1 < nbins) ? binTotal[i1] : 0;
    int pair = c0 + c1;
    s[tid] = pair;
    __syncthreads();
    for (int off = 1; off < 1024; off <<= 1) {
        int add = (tid >= off) ? s[tid - off] : 0;
        __syncthreads();
        s[tid] += add;
        __syncthreads();
    }
    int excl = s[tid] - pair;
    if (i0 < nbins) binStart[i0] = excl;
    if (i1 < nbins) binStart[i1] = excl + c0;
    if (tid == 1023) binStart[nbins] = s[1023];   // == E
}

// ---- 3) scatter: deterministic global position = binStart[b] +
//          hist[b*NB+blk] + LDS-local rank. Only LDS atomics.
__global__ __launch_bounds__(1024) void scatter_kernel(
        const int* __restrict__ X, int E, int chunk,
        const int* __restrict__ hist, const int* __restrict__ binStart,
        unsigned* __restrict__ sorted, int nbins) {
    __shared__ int cur[MAXBINS];
    int blk = blockIdx.x;
    for (int b = threadIdx.x; b < nbins; b += 1024)
        cur[b] = binStart[b] + hist[b * NB + blk];
    __syncthreads();
    int beg = blk * chunk;
    int end = min(beg + chunk, E);
    for (int i = beg + threadIdx.x; i < end; i += 1024) {
        int node = X[i];
        int b = node >> SHIFT;
        int pos = atomicAdd(&cur[b], 1);           // ds_add_rtn_u32
        sorted[pos] = (unsigned)i | ((unsigned)(node & (NPB - 1)) << 24);
    }
}

// ---- 4) gather: one block per bin, LDS acc[64][32], 4-deep MLP per group.
__global__ __launch_bounds__(256) void gather_kernel(
        const float* __restrict__ H,
        const unsigned* __restrict__ sorted,
        const int* __restrict__ binStart,
        float* __restrict__ out,
        int nbins, int nnodes) {
    __shared__ float acc[NPB * 32];
    int bin = blockIdx.x;
    int s   = binStart[bin];
    int end = binStart[bin + 1];

    for (int i = threadIdx.x; i < NPB * 32; i += 256) acc[i] = 0.0f;
    __syncthreads();

    int col = threadIdx.x & 31;    // lane->col: 2 lanes/bank on ds_add = free
    int grp = threadIdx.x >> 5;    // 8 groups of 32 lanes
    int i = s + grp;
    // main: 4 edges per group in flight (independent load chains)
    for (; i + 24 < end; i += 32) {
        unsigned p0 = sorted[i];
        unsigned p1 = sorted[i + 8];
        unsigned p2 = sorted[i + 16];
        unsigned p3 = sorted[i + 24];
        float v0 = H[(long long)(p0 & 0xFFFFFFu) * 32 + col];
        float v1 = H[(long long)(p1 & 0xFFFFFFu) * 32 + col];
        float v2 = H[(long long)(p2 & 0xFFFFFFu) * 32 + col];
        float v3 = H[(long long)(p3 & 0xFFFFFFu) * 32 + col];
        unsafeAtomicAdd(&acc[(p0 >> 24) * 32 + col], v0);
        unsafeAtomicAdd(&acc[(p1 >> 24) * 32 + col], v1);
        unsafeAtomicAdd(&acc[(p2 >> 24) * 32 + col], v2);
        unsafeAtomicAdd(&acc[(p3 >> 24) * 32 + col], v3);
    }
    for (; i < end; i += 8) {
        unsigned p = sorted[i];
        float v = H[(long long)(p & 0xFFFFFFu) * 32 + col];
        unsafeAtomicAdd(&acc[(p >> 24) * 32 + col], v);
    }
    __syncthreads();

    int node_base = bin << SHIFT;
    for (int i2 = threadIdx.x; i2 < NPB * 32; i2 += 256) {
        int node = node_base + (i2 >> 5);
        if (node < nnodes) out[(long long)node * 32 + (i2 & 31)] = acc[i2];
    }
}

// ---- Fallback (R3): one thread per (edge,col), straight device atomics.
__global__ void AggrSum_46299747451335_kernel(const float* __restrict__ H,
                                              const int* __restrict__ X_node,
                                              float* __restrict__ out,
                                              int num_edges) {
    long long t = (long long)blockIdx.x * blockDim.x + threadIdx.x;
    long long total = (long long)num_edges * 32;
    if (t >= total) return;
    int edge = (int)(t >> 5);
    int col  = (int)(t & 31);
    int node = X_node[edge];
    float v = H[t];
    unsafeAtomicAdd(&out[(long long)node * 32 + col], v);
}

extern "C" void kernel_launch(void* const* d_in, const int* in_sizes, int n_in,
                              void* d_out, int out_size, void* d_ws, size_t ws_size,
                              hipStream_t stream) {
    const float* H      = (const float*)d_in[0];
    const int*   X_node = (const int*)d_in[1];
    float*       out    = (float*)d_out;

    const int num_edges = in_sizes[0] / 32;   // H is [num_edges, 32]
    const int num_nodes = out_size / 32;      // out is [num_nodes, 32]
    const int nbins     = (num_nodes + NPB - 1) >> SHIFT;
    const int chunk     = (num_edges + NB - 1) / NB;

    // ws layout: hist[MAXBINS*NB] | binTotal[MAXBINS] | binStart[MAXBINS+1] | sorted[E]
    size_t off_hist   = 0;
    size_t off_total  = off_hist  + (size_t)MAXBINS * NB * sizeof(int);
    size_t off_start  = off_total + (size_t)MAXBINS * sizeof(int);
    size_t off_sorted = off_start + (size_t)(MAXBINS + 1) * sizeof(int);
    size_t need       = off_sorted + (size_t)num_edges * sizeof(unsigned);

    if (nbins <= MAXBINS && num_edges < (1 << 24) && ws_size >= need) {
        char* ws = (char*)d_ws;
        int*      hist     = (int*)(ws + off_hist);
        int*      binTotal = (int*)(ws + off_total);
        int*      binStart = (int*)(ws + off_start);
        unsigned* sorted   = (unsigned*)(ws + off_sorted);

        hist_kernel<<<NB, 1024, 0, stream>>>(X_node, num_edges, chunk,
                                             hist, nbins);
        scanA_kernel<<<nbins, NB, 0, stream>>>(hist, binTotal);
        scanB_kernel<<<1, 1024, 0, stream>>>(binTotal, binStart, nbins);
        scatter_kernel<<<NB, 1024, 0, stream>>>(X_node, num_edges, chunk,
                                                hist, binStart, sorted, nbins);
        gather_kernel<<<nbins, 256, 0, stream>>>(H, sorted, binStart, out,
                                                 nbins, num_nodes);
    } else {
        // Fallback: proven R3 path.
        hipMemsetAsync(d_out, 0, (size_t)out_size * sizeof(float), stream);
        long long total_threads = (long long)num_edges * 32;
        int block = 256;
        long long grid = (total_threads + block - 1) / block;
        AggrSum_46299747451335_kernel<<<(dim3)(unsigned)grid, block, 0, stream>>>(
            H, X_node, out, num_edges);
    }
}